// Round 4
// baseline (3658.626 us; speedup 1.0000x reference)
//
#include <hip/hip_runtime.h>
#include <cstdint>
#include <cstddef>

typedef unsigned short u16;
typedef __attribute__((ext_vector_type(8))) short short8;
typedef __attribute__((ext_vector_type(4))) short short4v;
typedef __attribute__((ext_vector_type(4))) float f32x4;

#define SEQ 128
#define BATCH 256
#define HID 1024
#define LSZ 262144

#define MFMA(a,b,c) __builtin_amdgcn_mfma_f32_16x16x32_bf16((a),(b),(c),0,0,0)

__device__ __forceinline__ u16 f2b(float f) {
  union { float f; unsigned u; } v; v.f = f;
  unsigned r = (v.u + 0x7FFFu + ((v.u >> 16) & 1u)) >> 16;
  return (u16)r;
}
__device__ __forceinline__ float b2f(u16 h) {
  union { unsigned u; float f; } v; v.u = ((unsigned)h) << 16; return v.f;
}
__device__ __forceinline__ float sigm(float x){ return 1.f/(1.f + __expf(-x)); }
__device__ __forceinline__ float tanh_f(float x){
  x = fminf(15.f, fmaxf(-15.f, x));
  float e = __expf(2.f*x); return (e-1.f)/(e+1.f);
}
__device__ __forceinline__ float eluf(float x){ return x > 0.f ? x : expm1f(x); }

// ---- asm loads: issue time is OURS (compiler cannot sink), counted via vmcnt ----
// B (weight) loads: plain cacheable -> L2-resident.
__device__ __forceinline__ void gload(const u16* p, short8& d) {
  asm volatile("global_load_dwordx4 %0, %1, off" : "=&v"(d) : "v"(p) : "memory");
}
// streaming single-use reads (xf, h1u archive): non-temporal, don't evict weights
__device__ __forceinline__ void gload_nt(const u16* p, short8& d) {
  asm volatile("global_load_dwordx4 %0, %1, off nt" : "=&v"(d) : "v"(p) : "memory");
}
// coherent cross-XCD reads (h0u): bypass local caches; NO nt (latency path)
__device__ __forceinline__ void gload_cg(const u16* p, short8& d) {
  asm volatile("global_load_dwordx4 %0, %1, off sc0 sc1" : "=&v"(d) : "v"(p) : "memory");
}
// h-state store: write-through coherent (8B); NO nt (visibility/ack path)
__device__ __forceinline__ void store_cg2(u16* p, short4v v) {
  asm volatile("global_store_dwordx2 %0, %1, off sc0 sc1" :: "v"(p), "v"(v) : "memory");
}
__device__ __forceinline__ void wait_vm0() {
  asm volatile("s_waitcnt vmcnt(0)" ::: "memory");
}
// flags: 1 per 128B line, plain store/load with sc0 sc1 (memory-side fresh, no RMW)
__device__ __forceinline__ void flag_set(int* p, int val) {
  asm volatile("global_store_dword %0, %1, off sc0 sc1" :: "v"(p), "v"(val) : "memory");
}
__device__ __forceinline__ void waitgroup(const int* f, int tgt) {
  if (threadIdx.x < 32) {
    const int* p = f + threadIdx.x * 32;
    while (true) {
      int v;
      asm volatile("global_load_dword %0, %1, off sc0 sc1\n\ts_waitcnt vmcnt(0)"
                   : "=v"(v) : "v"(p) : "memory");
      if (v >= tgt) break;
      __builtin_amdgcn_s_sleep(1);
    }
  }
  __syncthreads();
}

#define TIES_VB(vB) "+v"(vB[0][0]),"+v"(vB[0][1]),"+v"(vB[0][2]),"+v"(vB[0][3]), \
                    "+v"(vB[1][0]),"+v"(vB[1][1]),"+v"(vB[1][2]),"+v"(vB[1][3]), \
                    "+v"(vB[2][0]),"+v"(vB[2][1]),"+v"(vB[2][2]),"+v"(vB[2][3]), \
                    "+v"(vB[3][0]),"+v"(vB[3][1]),"+v"(vB[3][2]),"+v"(vB[3][3])
#define TIES_SV "+v"(sv[0]),"+v"(sv[1]),"+v"(sv[2]),"+v"(sv[3])

// ---------------- workspace layout (bytes) ----------------
static const size_t OFF_W0F  = 0;           // 32cg*34kb*8ct*512*2 = 8912896
static const size_t OFF_W1F  = 8912896;     // 32*64*8*512*2 = 16777216
static const size_t OFF_XF   = 25690112;    // 128t*16grt*2kb*512*2 = 4194304
static const size_t OFF_H0U  = 29884416;    // 2 slots * 524288
static const size_t OFF_FLG  = 30932992;    // 512 flags * 128B = 65536 (old c0 region)
static const size_t OFF_H1U  = 33030144;    // 129 slots * 524288 = 67633152 (slot t+1 == hs[t])
static const size_t OFF_BS0  = 100663296;
static const size_t OFF_BS1  = 100679680;
static const size_t OFF_MU   = 100697088;
static const size_t OFF_RSTD = 100828160;
static const size_t OFF_W1LN = 100959232;
static const size_t OFF_S1   = 102007808;
static const size_t OFF_B1P  = 102009856;
static const size_t OFF_W2B  = 102011904;
static const size_t OFF_W3B  = 102142976;
static const size_t OFF_A1   = 102159360;   // 33554432 -> end 135713792
static const size_t OFF_A2   = 0;           // alias dead w0f
static const size_t OFF_A3   = 8912896;     // alias dead w1f

// ---------------- prep: weights into fragment-linear tiles ----------------
// tile(cg 32h, kb, ct 0..7): 16 cols x 32 k; col c = g*32+hl, ct = c>>4
__global__ void prep_wf(const float* __restrict__ wih, const float* __restrict__ whh,
                        u16* __restrict__ out, int nkb, int kx) {
  int b = blockIdx.x; int cg = b >> 3, ct = b & 7;
  int g = ct >> 1;
  int n = nkb << 9;
  for (int e = threadIdx.x; e < n; e += 256) {
    int kb = e >> 9, r = e & 511;
    int q = r >> 7, col16 = (r >> 3) & 15, j = r & 7;
    int hl = (ct & 1) * 16 + col16;
    int gr = g * HID + cg * 32 + hl;
    int k = kb * 32 + q * 8 + j;
    float w = (k < kx) ? wih[(size_t)gr * kx + k] : whh[(size_t)gr * HID + (k - kx)];
    out[((size_t)(cg * nkb + kb) * 8 + ct) * 512 + r] = f2b(w);
  }
}

__global__ void prep_w1ln(const float* __restrict__ w1, const float* __restrict__ lng,
                          const float* __restrict__ lnb, const float* __restrict__ b1,
                          u16* __restrict__ w1ln, float* __restrict__ S1, float* __restrict__ b1p) {
  int j = blockIdx.x;
  float s = 0.f, bb = 0.f;
  for (int k = threadIdx.x; k < HID; k += 256) {
    float w = w1[(size_t)j * HID + k];
    u16 q = f2b(w * lng[k]);
    w1ln[(size_t)j * HID + k] = q;
    s += b2f(q);
    bb += w * lnb[k];
  }
  __shared__ float r1[256], r2[256];
  r1[threadIdx.x] = s; r2[threadIdx.x] = bb;
  __syncthreads();
  for (int o = 128; o > 0; o >>= 1) {
    if (threadIdx.x < (unsigned)o) { r1[threadIdx.x] += r1[threadIdx.x+o]; r2[threadIdx.x] += r2[threadIdx.x+o]; }
    __syncthreads();
  }
  if (threadIdx.x == 0) { S1[j] = r1[0]; b1p[j] = b1[j] + r2[0]; }
}

__global__ void prep_misc(const float* bih0, const float* bhh0, const float* bih1, const float* bhh1,
                          const float* x, const float* h0in,
                          const float* w2, const float* w3,
                          float* bs0, float* bs1, u16* xf, u16* h0u, u16* h1u,
                          u16* w2b, u16* w3b, int* flg) {
  size_t i = (size_t)blockIdx.x * blockDim.x + threadIdx.x;
  if (i < 4096) { bs0[i] = bih0[i] + bhh0[i]; return; }
  i -= 4096;
  if (i < 4096) { bs1[i] = bih1[i] + bhh1[i]; return; }
  i -= 4096;
  if (i < 2097152) {
    int o = (int)i;
    int r = o & 511, tile = o >> 9;
    int q = r >> 7, rl = (r >> 3) & 15, j = r & 7;
    int kb = tile & 1, v = tile >> 1;
    int grt = v & 15, t = v >> 4;
    int row = grt * 16 + rl, k = kb * 32 + q * 8 + j;
    xf[o] = f2b(x[((size_t)t * BATCH + row) * 64 + k]);
    return;
  }
  i -= 2097152;
  if (i < 262144) {   // h0u slot 0, UNMASKED initial h0 (layer0)
    int o = (int)i;
    int r = o & 511, tile = o >> 9;
    int q = r >> 7, rl = (r >> 3) & 15, j = r & 7;
    int grt = tile >> 5, kb = tile & 31;
    int row = grt * 16 + rl, h = kb * 32 + q * 8 + j;
    h0u[o] = f2b(h0in[(size_t)row * HID + h]);
    return;
  }
  i -= 262144;
  if (i < 262144) {   // h1u slot 0, UNMASKED initial h1
    int o = (int)i;
    int r = o & 511, tile = o >> 9;
    int q = r >> 7, rl = (r >> 3) & 15, j = r & 7;
    int grt = tile >> 5, kb = tile & 31;
    int row = grt * 16 + rl, h = kb * 32 + q * 8 + j;
    h1u[o] = f2b(h0in[LSZ + (size_t)row * HID + h]);
    return;
  }
  i -= 262144;
  if (i < 65536) { w2b[i] = f2b(w2[i]); return; }
  i -= 65536;
  if (i < 8192) { w3b[i] = f2b(w3[i]); return; }
  i -= 8192;
  if (i < 512) { flg[i * 32] = 0; return; }
}

// ---------------- persistent LSTM recurrence ----------------
// 512 blocks x 256 thr, 2 blocks/CU (launch_bounds(256,2), 32KB LDS each).
// bid = half*256 + (layer*128 + (rgblk&3)*32 + cg); rgblk = (bid>>5 &3) | half<<2.
// Blocks b and b+256 share (layer,cg) -> same weight stream, different rgblk ->
// INDEPENDENT dependency chains overlap on one CU (latency hiding via TLP).
// block tile: 32 rows (rgblk, 8 groups) x 128 gate-cols (cg).
// waves: wgr(2, 16-row strip) x wgc(2, 64-col half); wave-tile 16r x 64c, acc[4].
// K-loop: 8-kb chunks, all-asm loads, counted vmcnt pipeline (16/20/32/16).
// L1 K-ORDER REMAP: Whh*h1 chunks (stale g1) first; g0 checked at c==3.
__global__ __launch_bounds__(256, 2) void lstm_persist(
    const u16* __restrict__ w0f, const u16* __restrict__ w1f, const u16* __restrict__ xf,
    u16* __restrict__ h0u, u16* __restrict__ h1u,
    const float* __restrict__ c0all,
    const float* __restrict__ bs0, const float* __restrict__ bs1,
    const int* __restrict__ done, int* __restrict__ flg,
    float* __restrict__ dout)
{
  const int bid = blockIdx.x;
  const int half = bid >> 8;
  const int r0 = bid & 255;
  const int layer = r0 >> 7;
  const int rgblk = ((r0 >> 5) & 3) | (half << 2);   // 0..7
  const int cg = r0 & 31;
  const int tid = threadIdx.x;
  const int lane = tid & 63, wv = tid >> 6;
  const int wgr = wv & 1, wgc = wv >> 1;
  const int quad = lane >> 4, c16 = lane & 15;
  const int NKB = layer ? 64 : 34;
  const int NC  = layer ? 8 : 5;    // 8-kb chunks
  const int NH  = layer ? 16 : 9;   // 4-kb halves
  const u16* Wf = layer ? w1f : w0f;
  const float* bs = layer ? bs1 : bs0;
  const float* cb = c0all + (size_t)layer * LSZ;
  int* myf = flg + ((size_t)((layer * 8 + rgblk) * 32 + cg)) * 32;
  int* g0  = flg + (size_t)((0 + rgblk) * 32) * 32;
  int* g1  = flg + (size_t)((8 + rgblk) * 32) * 32;

  __shared__ __align__(16) u16 smem[16384];  // 2 x 16KB A-chunk buffers; epilogue gl (16KB) aliases
  float* gl = (float*)smem;

  // staging: wave -> (sg = row-group 0/1, kq = kb quarter 0/1), 4 loads/chunk/wave
  const int sg = wv & 1, kq = wv >> 1;
  const int sgrt = rgblk * 2 + sg;               // global 16-row group 0..15
  const int woff = lane * 8;                     // u16 offset in tile
  const int srow = rgblk * 32 + sg * 16 + (lane & 15);
  const short8 z8 = {0,0,0,0,0,0,0,0};

  // c-state in registers all 128 steps: thread owns (row = tid>>3, 4 h-cols at q=tid&7)
  float creg[4];
  {
    const float* cp0 = cb + (size_t)(rgblk * 32 + (tid >> 3)) * HID + cg * 32 + (tid & 7) * 4;
    #pragma unroll
    for (int j = 0; j < 4; ++j) creg[j] = cp0[j];
  }

  for (int t = 0; t < SEQ; ++t) {
    // stale-first flag order; L1's fresh g0 check deferred to mid-step
    if (layer == 0) {
      if (t >= 2) waitgroup(g1, t - 1);
      if (t >= 1) waitgroup(g0, t);
    } else {
      if (t >= 1) waitgroup(g1, t);
    }

    int sdone = done[t * BATCH + srow];
    asm volatile("" : "+v"(sdone));

    f32x4 acc[4];
    #pragma unroll
    for (int i = 0; i < 4; ++i) acc[i] = (f32x4){0,0,0,0};
    short8 sv[4];
    short8 vBa[4][4], vBb[4][4];

    // logical->phys chunk/half remap: L1 rotates by 4 chunks (h1-half first)
    auto PC = [&](int lc) { return layer ? ((lc + 4) & 7) : lc; };

    // issue 4 staged-A loads for LOGICAL chunk lc; tail clamped (L2-hit repeat)
    auto issueA = [&](int lc) {
      int kb0 = PC(lc) * 8 + kq * 4;
      #pragma unroll
      for (int kbl = 0; kbl < 4; ++kbl) {
        int kb = kb0 + kbl;
        if (kb > NKB - 1) kb = NKB - 1;
        if (layer == 0) {
          if (kb < 2) {
            gload_nt(xf + ((size_t)((t * 16 + sgrt) * 2 + kb)) * 512 + woff, sv[kbl]);
          } else {
            gload_cg(h0u + (size_t)(t & 1) * 262144 + (size_t)(sgrt * 32 + (kb - 2)) * 512 + woff, sv[kbl]);
          }
        } else {
          if (kb < 32) {
            gload_cg(h0u + (size_t)((t + 1) & 1) * 262144 + (size_t)(sgrt * 32 + kb) * 512 + woff, sv[kbl]);
          } else {
            gload_nt(h1u + (size_t)t * 262144 + (size_t)(sgrt * 32 + (kb - 32)) * 512 + woff, sv[kbl]);
          }
        }
      }
    };
    // commit staged A regs -> LDS buffer (lc&1), applying the done reset mask
    // chunk buffer: 16 tiles, tile id = kbl*2 + sg
    auto commitA = [&](int lc) {
      int kb0 = PC(lc) * 8 + kq * 4;
      int bo = (lc & 1) << 13;       // 8192 u16 per buffer
      u16* d = &smem[bo + (kq * 8 + sg) * 512 + woff];
      #pragma unroll
      for (int kbl = 0; kbl < 4; ++kbl) {
        int kb = kb0 + kbl;
        int maskable = layer ? (kb >= 32) : (kb >= 2);
        short8 v = sv[kbl];
        if (maskable && sdone) v = z8;
        *(short8*)(d + kbl * 1024) = v;   // tile (kq*4+kbl)*2 + sg
      }
    };
    // issue 16 B loads for LOGICAL half lh; tail clamped (L2-hit repeat)
    auto issueB = [&](int lh, short8 (&vB)[4][4]) {
      int ph = layer ? ((lh + 8) & 15) : lh;
      int kk = ph * 4;
      #pragma unroll
      for (int kbl = 0; kbl < 4; ++kbl) {
        int kbx = kk + kbl;
        if (kbx > NKB - 1) kbx = NKB - 1;
        #pragma unroll
        for (int ct = 0; ct < 4; ++ct)
          gload(Wf + ((size_t)(cg * NKB + kbx) * 8 + wgc * 4 + ct) * 512 + lane * 8, vB[kbl][ct]);
      }
    };
    auto comp4 = [&](int lh, short8 (&vB)[4][4]) {
      int ph = layer ? ((lh + 8) & 15) : lh;
      int kbc4 = NKB - ph * 4; if (kbc4 > 4) kbc4 = 4;
      int bo = ((lh >> 1) & 1) << 13;
      int tb = (lh & 1) * 4;
      #pragma unroll
      for (int kbl = 0; kbl < 4; ++kbl) if (kbl < kbc4) {
        short8 af = *(const short8*)&smem[bo + ((tb + kbl) * 2 + wgr) * 512 + lane * 8];
        #pragma unroll
        for (int ct = 0; ct < 4; ++ct)
          acc[ct] = MFMA(af, vB[kbl][ct], acc[ct]);
      }
    };

    // ---- prologue: B(0)[16] A(0)[4] B(1)[16] = 36 in flight; retire B0+A0, keep B1 ----
    issueB(0, vBa);
    issueA(0);
    issueB(1, vBb);
    asm volatile("s_waitcnt vmcnt(16)" : TIES_SV, TIES_VB(vBa) :: "memory");
    __builtin_amdgcn_sched_barrier(0);
    commitA(0);
    __syncthreads();

    // ---- main loop: invariant at top = B(2c+1) [16] in flight ----
    for (int c = 0; c < NC - 1; ++c) {
      // L1: gate on L0's fresh broadcast only when about to prefetch phys chunk 0
      if (layer && c == 3) waitgroup(g0, t + 1);
      issueA(c + 1);                                   // -> 20
      comp4(2 * c, vBa);
      issueB(2 * c + 2, vBa);                          // -> 36
      asm volatile("s_waitcnt vmcnt(20)" : TIES_VB(vBb) :: "memory");  // B(2c+1) ready
      __builtin_amdgcn_sched_barrier(0);
      comp4(2 * c + 1, vBb);
      issueB(2 * c + 3, vBb);                          // -> 36
      asm volatile("s_waitcnt vmcnt(32)" : TIES_SV :: "memory");       // A(c+1) ready
      __builtin_amdgcn_sched_barrier(0);
      commitA(c + 1);
      asm volatile("s_waitcnt vmcnt(16)" : TIES_VB(vBa) :: "memory");  // B(2c+2) ready
      __builtin_amdgcn_sched_barrier(0);
      __syncthreads();                                 // leaves B(2c+3) [16] in flight
    }
    // ---- tail chunk ----
    {
      int c = NC - 1;
      comp4(2 * c, vBa);
      asm volatile("s_waitcnt vmcnt(0)" : TIES_VB(vBb) :: "memory");
      __builtin_amdgcn_sched_barrier(0);
      if (2 * c + 1 < NH) comp4(2 * c + 1, vBb);
      __syncthreads();   // protect gl alias (buffer 0) from in-flight comp reads
    }

    // epilogue: gates -> LDS gl[row32][col128]
    #pragma unroll
    for (int ct = 0; ct < 4; ++ct)
      #pragma unroll
      for (int rgi = 0; rgi < 4; ++rgi) {
        int row0 = wgr * 16 + quad * 4 + rgi;
        int col = wgc * 64 + ct * 16 + c16;
        gl[row0 * 128 + col] = acc[ct][rgi];
      }
    __syncthreads();

    {
      int row = tid >> 3;           // 0..31
      int q = tid & 7;              // 4 h-cols per thread
      int rowg = rgblk * 32 + row;
      int H0 = cg * 32 + q * 4;
      const float* glp = gl + row * 128;
      float m = done[t * BATCH + rowg] ? 0.f : 1.f;
      short4v hv;
      float h2a[4];
      #pragma unroll
      for (int j = 0; j < 4; ++j) {
        int cl = q * 4 + j;
        float ivv = glp[cl]      + bs[H0 + j];
        float fvv = glp[32 + cl] + bs[HID + H0 + j];
        float gvv = glp[64 + cl] + bs[2*HID + H0 + j];
        float ovv = glp[96 + cl] + bs[3*HID + H0 + j];
        float c2 = sigm(fvv) * (creg[j] * m) + sigm(ivv) * tanh_f(gvv);
        float h2 = sigm(ovv) * tanh_f(c2);
        creg[j] = c2;
        h2a[j] = h2;
        ((u16*)&hv)[j] = f2b(h2);
      }
      // frag-layout store: tile = (global grt)*32 + cg; elem = (qq*16 + rl)*8 + jj0
      size_t off = (size_t)((rgblk * 2 + (row >> 4)) * 32 + cg) * 512
                 + (size_t)(((q >> 1) * 16 + (row & 15)) * 8 + (q & 1) * 4);
      if (layer == 0) store_cg2(h0u + (size_t)((t + 1) & 1) * 262144 + off, hv);
      else            store_cg2(h1u + (size_t)(t + 1) * 262144 + off, hv);
      if (t == SEQ - 1) {
        float* dh = dout + 32768 + (size_t)layer * LSZ + (size_t)rowg * HID + H0;
        float* dc = dout + 32768 + 2 * LSZ + (size_t)layer * LSZ + (size_t)rowg * HID + H0;
        #pragma unroll
        for (int j = 0; j < 4; ++j) { dh[j] = h2a[j]; dc[j] = creg[j]; }
      }
    }
    wait_vm0();          // drain h stores (write-through acked)
    __syncthreads();
    if (tid == 0) flag_set(myf, t + 1);
  }
}

// ---------------- LayerNorm row stats (reads h1u frag layout) ----------------
__global__ void ln_stats(const u16* __restrict__ h1u, float* __restrict__ mu, float* __restrict__ rstd) {
  int R = blockIdx.x * 4 + (threadIdx.x >> 6);
  int l = threadIdx.x & 63;
  int t = R >> 8, brow = R & 255, grt = brow >> 4, rl = brow & 15;
  const u16* base = h1u + (size_t)(t + 1) * 262144 + (size_t)(grt * 32 + (l >> 1)) * 512;
  int q2 = (l & 1) * 2;
  short8 v0 = *(const short8*)(base + (q2 * 16 + rl) * 8);
  short8 v1 = *(const short8*)(base + ((q2 + 1) * 16 + rl) * 8);
  float s = 0.f, q = 0.f;
  #pragma unroll
  for (int e = 0; e < 8; ++e) {
    float a = b2f((u16)v0[e]); s += a; q += a*a;
    float b = b2f((u16)v1[e]); s += b; q += b*b;
  }
  for (int o = 32; o > 0; o >>= 1) { s += __shfl_xor(s, o); q += __shfl_xor(q, o); }
  if (l == 0) {
    float mm = s * (1.f/1024.f);
    float var = q * (1.f/1024.f) - mm*mm;
    mu[R] = mm; rstd[R] = rsqrtf(var + 1e-5f);
  }
}

// ---------------- MLP GEMM: 128x128 tile, amode1 = A in h1u frag layout ----------------
__global__ __launch_bounds__(512, 4) void mlp_gemm(
    const u16* __restrict__ A, int lda, int amode,
    const u16* __restrict__ B, int K, int N,
    u16* __restrict__ out, int ldo, int mode, int swiz,
    const float* __restrict__ mu, const float* __restrict__ rstd,
    const float* __restrict__ S1v, const float* __restrict__ bias)
{
  int nt, mtb;
  if (swiz) { int p = blockIdx.x * gridDim.y + blockIdx.y; nt = p & 3; mtb = p >> 2; }
  else { nt = blockIdx.x; mtb = blockIdx.y; }
  const int tid = threadIdx.x, lane = tid & 63, wv = tid >> 6;
  const int quad = lane >> 4, c16 = lane & 15;
  __shared__ __align__(16) u16 Am[16384], Bm[16384];
  f32x4 acc[8];
  #pragma unroll
  for (int i = 0; i < 8; ++i) acc[i] = (f32x4){0.f,0.f,0.f,0.f};

  int arow[4], akl[4], bcol[4];
  #pragma unroll
  for (int i = 0; i < 4; ++i) {
    int s = tid + i * 512, sub = s >> 6, lp = s & 63;
    int ks = sub >> 3, u = sub & 7;
    arow[i] = mtb * 128 + u * 16 + (lp & 15);
    akl[i]  = ks * 32 + (lp >> 4) * 8;
    bcol[i] = nt * 128 + u * 16 + (lp & 15);
  }
  short8 vA[4], vB[4];
  const short8 z8 = {0,0,0,0,0,0,0,0};
  const int NCH = K >> 7;
  auto load_stage = [&](int ci) {
    int kc = ci << 7;
    #pragma unroll
    for (int i = 0; i < 4; ++i) {
      if (amode) {
        int R = arow[i], k = kc + akl[i];
        const u16* p = A + (size_t)((R >> 8) + 1) * 262144
                         + (size_t)(((R >> 4) & 15) * 32 + (k >> 5)) * 512
                         + (size_t)((((k >> 3) & 3) * 16 + (R & 15)) * 8);
        vA[i] = *(const short8*)p;
      } else {
        vA[i] = *(const short8*)(A + (size_t)arow[i] * lda + kc + akl[i]);
      }
      vB[i] = (bcol[i] < N) ? *(const short8*)(B + (size_t)bcol[i] * K + kc + akl[i]) : z8;
    }
  };
  load_stage(0);
  for (int ci = 0; ci < NCH; ++ci) {
    #pragma unroll
    for (int i = 0; i < 4; ++i) {
      *(short8*)&Am[(size_t)(tid + i*512) * 8] = vA[i];
      *(short8*)&Bm[(size_t)(tid + i*512) * 8] = vB[i];
    }
    __syncthreads();
    if (ci + 1 < NCH) load_stage(ci + 1);
    #pragma unroll
    for (int ks = 0; ks < 4; ++ks) {
      short8 bf = *(const short8*)&Bm[((ks*8 + wv)*64 + lane) * 8];
      #pragma unroll
      for (int rt = 0; rt < 8; ++rt) {
        short8 af = *(const short8*)&Am[((ks*8 + rt)*64 + lane) * 8];
        acc[rt] = MFMA(af, bf, acc[rt]);
      }
    }
    __syncthreads();
  }
  int col = nt * 128 + wv * 16 + c16;
  if (col < N) {
    #pragma unroll
    for (int rt = 0; rt < 8; ++rt) {
      #pragma unroll
      for (int rgi = 0; rgi < 4; ++rgi) {
        int row = mtb * 128 + rt * 16 + quad * 4 + rgi;
        float v = acc[rt][rgi];
        if (mode == 0) v = v * rstd[row] - mu[row] * rstd[row] * S1v[col] + bias[col];
        else           v = v + bias[col];
        v = eluf(v);
        out[(size_t)row * ldo + col] = f2b(v);
      }
    }
  }
}

__global__ void value_head(const u16* __restrict__ a3, const float* __restrict__ wv,
                           const float* __restrict__ bv, float* __restrict__ dout) {
  int row = blockIdx.x * 256 + threadIdx.x;
  const short8* p = (const short8*)(a3 + (size_t)row * 64);
  float s = bv[0];
  #pragma unroll
  for (int j = 0; j < 8; ++j) {
    short8 v = p[j];
    #pragma unroll
    for (int e = 0; e < 8; ++e) s += b2f((u16)v[e]) * wv[j*8+e];
  }
  dout[row] = s;
}

extern "C" void kernel_launch(void* const* d_in, const int* in_sizes, int n_in,
                              void* d_out, int out_size, void* d_ws, size_t ws_size,
                              hipStream_t stream) {
  (void)in_sizes; (void)n_in; (void)out_size; (void)ws_size;
  const float* x    = (const float*)d_in[0];
  const int*   done = (const int*)d_in[1];
  const float* h0in = (const float*)d_in[2];
  const float* c0in = (const float*)d_in[3];
  const float* wih0 = (const float*)d_in[4];
  const float* whh0 = (const float*)d_in[5];
  const float* bih0 = (const float*)d_in[6];
  const float* bhh0 = (const float*)d_in[7];
  const float* wih1 = (const float*)d_in[8];
  const float* whh1 = (const float*)d_in[9];
  const float* bih1 = (const float*)d_in[10];
  const float* bhh1 = (const float*)d_in[11];
  const float* lng  = (const float*)d_in[12];
  const float* lnb  = (const float*)d_in[13];
  const float* w1   = (const float*)d_in[14];
  const float* b1   = (const float*)d_in[15];
  const float* w2   = (const float*)d_in[16];
  const float* b2   = (const float*)d_in[17];
  const float* w3   = (const float*)d_in[18];
  const float* b3   = (const float*)d_in[19];
  const float* wvp  = (const float*)d_in[20];
  const float* bvp  = (const float*)d_in[21];
  float* dout = (float*)d_out;
  char* ws = (char*)d_ws;

  u16*   w0f  = (u16*)(ws + OFF_W0F);
  u16*   w1f  = (u16*)(ws + OFF_W1F);
  u16*   xf   = (u16*)(ws + OFF_XF);
  u16*   h0u  = (u16*)(ws + OFF_H0U);
  u16*   h1u  = (u16*)(ws + OFF_H1U);
  float* bs0  = (float*)(ws + OFF_BS0);
  float* bs1  = (float*)(ws + OFF_BS1);
  int*   flg  = (int*)(ws + OFF_FLG);
  float* mu   = (float*)(ws + OFF_MU);
  float* rstd = (float*)(ws + OFF_RSTD);
  u16*   w1ln = (u16*)(ws + OFF_W1LN);
  float* s1   = (float*)(ws + OFF_S1);
  float* b1p  = (float*)(ws + OFF_B1P);
  u16*   w2b  = (u16*)(ws + OFF_W2B);
  u16*   w3b  = (u16*)(ws + OFF_W3B);
  u16*   a1   = (u16*)(ws + OFF_A1);
  u16*   a2   = (u16*)(ws + OFF_A2);
  u16*   a3   = (u16*)(ws + OFF_A3);

  prep_wf<<<256, 256, 0, stream>>>(wih0, whh0, w0f, 34, 64);
  prep_wf<<<256, 256, 0, stream>>>(wih1, whh1, w1f, 64, 1024);
  prep_w1ln<<<512, 256, 0, stream>>>(w1, lng, lnb, b1, w1ln, s1, b1p);
  prep_misc<<<12609, 256, 0, stream>>>(bih0, bhh0, bih1, bhh1, x, h0in, w2, w3,
                                       bs0, bs1, xf, h0u, h1u, w2b, w3b, flg);

  lstm_persist<<<512, 256, 0, stream>>>(w0f, w1f, xf, h0u, h1u, c0in,
                                        bs0, bs1, done, flg, dout);

  ln_stats<<<8192, 256, 0, stream>>>(h1u, mu, rstd);
  mlp_gemm<<<dim3(8, 128), 512, 0, stream>>>(h1u, 0, 1, w1ln, 1024, 512, a1, 512, 0, 1, mu, rstd, s1, b1p);
  mlp_gemm<<<dim3(1, 256), 512, 0, stream>>>(a1, 512, 0, w2b, 512, 128, a2, 128, 1, 0, mu, rstd, s1, b2);
  mlp_gemm<<<dim3(1, 256), 512, 0, stream>>>(a2, 128, 0, w3b, 128, 64, a3, 64, 1, 0, mu, rstd, s1, b3);
  value_head<<<128, 256, 0, stream>>>(a3, wvp, bvp, dout);
}

// Round 5
// 2937.521 us; speedup vs baseline: 1.2455x; 1.2455x over previous
//
#include <hip/hip_runtime.h>
#include <cstdint>
#include <cstddef>

typedef unsigned short u16;
typedef __attribute__((ext_vector_type(8))) short short8;
typedef __attribute__((ext_vector_type(4))) float f32x4;

#define SEQ 128
#define BATCH 256
#define HID 1024
#define LSZ 262144
#define RING 8

#define MFMA(a,b,c) __builtin_amdgcn_mfma_f32_16x16x32_bf16((a),(b),(c),0,0,0)

__device__ __forceinline__ u16 f2b(float f) {
  union { float f; unsigned u; } v; v.f = f;
  unsigned r = (v.u + 0x7FFFu + ((v.u >> 16) & 1u)) >> 16;
  return (u16)r;
}
__device__ __forceinline__ float b2f(u16 h) {
  union { unsigned u; float f; } v; v.u = ((unsigned)h) << 16; return v.f;
}
__device__ __forceinline__ float sigm(float x){ return 1.f/(1.f + __expf(-x)); }
__device__ __forceinline__ float tanh_f(float x){
  x = fminf(15.f, fmaxf(-15.f, x));
  float e = __expf(2.f*x); return (e-1.f)/(e+1.f);
}
__device__ __forceinline__ float eluf(float x){ return x > 0.f ? x : expm1f(x); }

// ---- asm loads: issue time is OURS (compiler cannot sink), counted via vmcnt ----
// B (weight) loads: plain cacheable -> L2-resident.
__device__ __forceinline__ void gload(const u16* p, short8& d) {
  asm volatile("global_load_dwordx4 %0, %1, off" : "=&v"(d) : "v"(p) : "memory");
}
// streaming single-use reads (xf, h1u archive): non-temporal, don't evict weights
__device__ __forceinline__ void gload_nt(const u16* p, short8& d) {
  asm volatile("global_load_dwordx4 %0, %1, off nt" : "=&v"(d) : "v"(p) : "memory");
}
// coherent cross-XCD reads (h0 ring, fresh h1): bypass local caches
__device__ __forceinline__ void gload_cg(const u16* p, short8& d) {
  asm volatile("global_load_dwordx4 %0, %1, off sc0 sc1" : "=&v"(d) : "v"(p) : "memory");
}
// h-state store: write-through coherent; NO nt (visibility/ack path)
__device__ __forceinline__ void store_cg(u16* p, short8 v) {
  asm volatile("global_store_dwordx4 %0, %1, off sc0 sc1" :: "v"(p), "v"(v) : "memory");
}
__device__ __forceinline__ void wait_vm0() {
  asm volatile("s_waitcnt vmcnt(0)" ::: "memory");
}
// flags: 1 per 128B line, plain store/load with sc0 sc1 (memory-side fresh, no RMW)
__device__ __forceinline__ void flag_set(int* p, int val) {
  asm volatile("global_store_dword %0, %1, off sc0 sc1" :: "v"(p), "v"(val) : "memory");
}
__device__ __forceinline__ void waitgroup(const int* f, int tgt) {
  if (threadIdx.x < 32) {
    const int* p = f + threadIdx.x * 32;
    while (true) {
      int v;
      asm volatile("global_load_dword %0, %1, off sc0 sc1\n\ts_waitcnt vmcnt(0)"
                   : "=v"(v) : "v"(p) : "memory");
      if (v >= tgt) break;
      __builtin_amdgcn_s_sleep(1);
    }
  }
  __syncthreads();
}

#define TIES_VB(vB) "+v"(vB[0][0]),"+v"(vB[0][1]),"+v"(vB[0][2]),"+v"(vB[0][3]), \
                    "+v"(vB[1][0]),"+v"(vB[1][1]),"+v"(vB[1][2]),"+v"(vB[1][3]), \
                    "+v"(vB[2][0]),"+v"(vB[2][1]),"+v"(vB[2][2]),"+v"(vB[2][3]), \
                    "+v"(vB[3][0]),"+v"(vB[3][1]),"+v"(vB[3][2]),"+v"(vB[3][3])
#define TIES_SV "+v"(sv[0]),"+v"(sv[1]),"+v"(sv[2]),"+v"(sv[3]),"+v"(sv[4]),"+v"(sv[5]),"+v"(sv[6]),"+v"(sv[7])

// ---------------- workspace layout (bytes) ----------------
static const size_t OFF_W0F  = 0;           // 32cg*34kb*8ct*512*2 = 8912896
static const size_t OFF_W1F  = 8912896;     // 32*64*8*512*2 = 16777216
static const size_t OFF_XF   = 25690112;    // 128t*16grt*2kb*512*2 = 4194304
static const size_t OFF_FLG  = 30932992;    // 256 flags * 128B = 32768
static const size_t OFF_H1U  = 33030144;    // 129 slots * 524288 (slot t+1 == hs[t])
static const size_t OFF_BS0  = 100663296;
static const size_t OFF_BS1  = 100679680;
static const size_t OFF_MU   = 100697088;
static const size_t OFF_RSTD = 100828160;
static const size_t OFF_W1LN = 100959232;
static const size_t OFF_S1   = 102007808;
static const size_t OFF_B1P  = 102009856;
static const size_t OFF_W2B  = 102011904;
static const size_t OFF_W3B  = 102142976;
static const size_t OFF_A1   = 102159360;   // 33554432 -> end 135713792
static const size_t OFF_H0R  = 102159360;   // h0 RING (8 x 524288 = 4MB) aliases A1:
                                            // ring used only during lstm_persist, a1 written after
static const size_t OFF_A2   = 0;           // alias dead w0f
static const size_t OFF_A3   = 8912896;     // alias dead w1f

// ---------------- prep: weights into fragment-linear tiles ----------------
// tile(cg 32h, kb, ct 0..7): 16 cols x 32 k; col c = g*32+hl, ct = c>>4
__global__ void prep_wf(const float* __restrict__ wih, const float* __restrict__ whh,
                        u16* __restrict__ out, int nkb, int kx) {
  int b = blockIdx.x; int cg = b >> 3, ct = b & 7;
  int g = ct >> 1;
  int n = nkb << 9;
  for (int e = threadIdx.x; e < n; e += 256) {
    int kb = e >> 9, r = e & 511;
    int q = r >> 7, col16 = (r >> 3) & 15, j = r & 7;
    int hl = (ct & 1) * 16 + col16;
    int gr = g * HID + cg * 32 + hl;
    int k = kb * 32 + q * 8 + j;
    float w = (k < kx) ? wih[(size_t)gr * kx + k] : whh[(size_t)gr * HID + (k - kx)];
    out[((size_t)(cg * nkb + kb) * 8 + ct) * 512 + r] = f2b(w);
  }
}

__global__ void prep_w1ln(const float* __restrict__ w1, const float* __restrict__ lng,
                          const float* __restrict__ lnb, const float* __restrict__ b1,
                          u16* __restrict__ w1ln, float* __restrict__ S1, float* __restrict__ b1p) {
  int j = blockIdx.x;
  float s = 0.f, bb = 0.f;
  for (int k = threadIdx.x; k < HID; k += 256) {
    float w = w1[(size_t)j * HID + k];
    u16 q = f2b(w * lng[k]);
    w1ln[(size_t)j * HID + k] = q;
    s += b2f(q);
    bb += w * lnb[k];
  }
  __shared__ float r1[256], r2[256];
  r1[threadIdx.x] = s; r2[threadIdx.x] = bb;
  __syncthreads();
  for (int o = 128; o > 0; o >>= 1) {
    if (threadIdx.x < (unsigned)o) { r1[threadIdx.x] += r1[threadIdx.x+o]; r2[threadIdx.x] += r2[threadIdx.x+o]; }
    __syncthreads();
  }
  if (threadIdx.x == 0) { S1[j] = r1[0]; b1p[j] = b1[j] + r2[0]; }
}

__global__ void prep_misc(const float* bih0, const float* bhh0, const float* bih1, const float* bhh1,
                          const float* x, const float* h0in,
                          const float* w2, const float* w3,
                          float* bs0, float* bs1, u16* xf, u16* h0r, u16* h1u,
                          u16* w2b, u16* w3b, int* flg) {
  size_t i = (size_t)blockIdx.x * blockDim.x + threadIdx.x;
  if (i < 4096) { bs0[i] = bih0[i] + bhh0[i]; return; }
  i -= 4096;
  if (i < 4096) { bs1[i] = bih1[i] + bhh1[i]; return; }
  i -= 4096;
  if (i < 2097152) {
    int o = (int)i;
    int r = o & 511, tile = o >> 9;
    int q = r >> 7, rl = (r >> 3) & 15, j = r & 7;
    int kb = tile & 1, v = tile >> 1;
    int grt = v & 15, t = v >> 4;
    int row = grt * 16 + rl, k = kb * 32 + q * 8 + j;
    xf[o] = f2b(x[((size_t)t * BATCH + row) * 64 + k]);
    return;
  }
  i -= 2097152;
  if (i < 262144) {   // h0 ring slot 0, UNMASKED initial h0 (layer0)
    int o = (int)i;
    int r = o & 511, tile = o >> 9;
    int q = r >> 7, rl = (r >> 3) & 15, j = r & 7;
    int grt = tile >> 5, kb = tile & 31;
    int row = grt * 16 + rl, h = kb * 32 + q * 8 + j;
    h0r[o] = f2b(h0in[(size_t)row * HID + h]);
    return;
  }
  i -= 262144;
  if (i < 262144) {   // h1u slot 0, UNMASKED initial h1
    int o = (int)i;
    int r = o & 511, tile = o >> 9;
    int q = r >> 7, rl = (r >> 3) & 15, j = r & 7;
    int grt = tile >> 5, kb = tile & 31;
    int row = grt * 16 + rl, h = kb * 32 + q * 8 + j;
    h1u[o] = f2b(h0in[LSZ + (size_t)row * HID + h]);
    return;
  }
  i -= 262144;
  if (i < 65536) { w2b[i] = f2b(w2[i]); return; }
  i -= 65536;
  if (i < 8192) { w3b[i] = f2b(w3[i]); return; }
  i -= 8192;
  if (i < 256) { flg[i * 32] = 0; return; }
}

// ---------------- persistent LSTM recurrence ----------------
// 256 blocks x 256 thr (round-3 geometry). bid = layer*128 + rg*32 + cg.
// LAYER DECOUPLING via 8-slot h0 ring: L0 (smaller K, faster) runs up to 7
// steps ahead of L1. L0's lap check (g1 >= t-7) and L1's h0 check (g0 >= t+1)
// are both pre-satisfied in steady state -> each layer's step chain is only
// its OWN recurrence (compute + same-rg flag RT); step period = max, not sum.
// K-loop: 8-kb chunks, all-asm loads, counted vmcnt (16/24/32/16), natural
// chunk order (L1: old h0 first, fresh h1 in 2nd half).
__global__ __launch_bounds__(256, 1) void lstm_persist(
    const u16* __restrict__ w0f, const u16* __restrict__ w1f, const u16* __restrict__ xf,
    u16* __restrict__ h0r, u16* __restrict__ h1u,
    const float* __restrict__ c0all,
    const float* __restrict__ bs0, const float* __restrict__ bs1,
    const int* __restrict__ done, int* __restrict__ flg,
    float* __restrict__ dout)
{
  const int bid = blockIdx.x;
  const int layer = bid >> 7;
  const int rg = (bid >> 5) & 3;
  const int cg = bid & 31;
  const int tid = threadIdx.x;
  const int lane = tid & 63, wv = tid >> 6;
  const int wgr = wv & 1, wgc = wv >> 1;
  const int quad = lane >> 4, c16 = lane & 15;
  const int NKB = layer ? 64 : 34;
  const int NC  = layer ? 8 : 5;    // 8-kb chunks
  const int NH  = layer ? 16 : 9;   // 4-kb halves
  const u16* Wf = layer ? w1f : w0f;
  const float* bs = layer ? bs1 : bs0;
  const float* cb = c0all + (size_t)layer * LSZ;
  int* fl0 = flg;
  int* fl1 = flg + 128 * 32;
  int* myf = (layer ? fl1 : fl0) + (rg * 32 + cg) * 32;
  int* g0 = fl0 + rg * 32 * 32;
  int* g1 = fl1 + rg * 32 * 32;

  __shared__ __align__(16) u16 smem[32768];  // 2 x 32KB A-chunk buffers; epilogue gl aliases
  float* gl = (float*)smem;

  // staging: wave wv stages 16-row group; per-instruction pattern = base + lane*16B
  const int sgrt = rg * 4 + wv;
  const int woff = (lane >> 4) * 128 + (lane & 15) * 8;   // u16 offset in tile (== lane*8)
  const int srow = rg * 64 + wv * 16 + (lane & 15);
  const short8 z8 = {0,0,0,0,0,0,0,0};

  // c-state lives in registers for all 128 steps (thread owns (row=tid>>2, q=tid&3))
  float creg[8];
  {
    const float* cp0 = cb + (size_t)(rg * 64 + (tid >> 2)) * HID + cg * 32 + (tid & 3) * 8;
    #pragma unroll
    for (int j = 0; j < 8; ++j) creg[j] = cp0[j];
  }

  for (int t = 0; t < SEQ; ++t) {
    // cold (pre-satisfied) checks first, hot own-recurrence check last
    if (layer == 0) {
      if (t >= RING) waitgroup(g1, t - (RING - 1));  // lap: L1 freed ring slot
      if (t >= 1)    waitgroup(g0, t);               // hot: own h0(t) ready
    } else {
      waitgroup(g0, t + 1);                          // cold: L0 is ~7 ahead
      if (t >= 1) waitgroup(g1, t);                  // hot: own h1(t) ready
    }

    int sdone = done[t * BATCH + srow];
    asm volatile("" : "+v"(sdone));

    f32x4 acc0[4], acc1[4];
    #pragma unroll
    for (int i = 0; i < 4; ++i) { acc0[i] = (f32x4){0,0,0,0}; acc1[i] = (f32x4){0,0,0,0}; }
    short8 sv[8];
    short8 vBa[4][4], vBb[4][4];

    // issue 8 staged-A loads for chunk c; tail clamped (L2-hit repeat)
    auto issueA = [&](int c) {
      int kb0 = c * 8;
      #pragma unroll
      for (int kbl = 0; kbl < 8; ++kbl) {
        int kb = kb0 + kbl;
        if (kb > NKB - 1) kb = NKB - 1;
        if (layer == 0) {
          if (kb < 2) {
            gload_nt(xf + ((size_t)((t * 16 + sgrt) * 2 + kb)) * 512 + woff, sv[kbl]);
          } else {
            gload_cg(h0r + (size_t)(t & (RING-1)) * 262144 + (size_t)(sgrt * 32 + (kb - 2)) * 512 + woff, sv[kbl]);
          }
        } else {
          if (kb < 32) {
            gload_cg(h0r + (size_t)((t + 1) & (RING-1)) * 262144 + (size_t)(sgrt * 32 + kb) * 512 + woff, sv[kbl]);
          } else {
            gload_cg(h1u + (size_t)t * 262144 + (size_t)(sgrt * 32 + (kb - 32)) * 512 + woff, sv[kbl]);
          }
        }
      }
    };
    // commit staged A regs -> LDS buffer (c&1), applying the done reset mask
    auto commitA = [&](int c) {
      int kb0 = c * 8;
      int bo = (c & 1) << 14;       // 16384 u16 per buffer
      u16* d = &smem[bo + wv * 512 + woff];
      #pragma unroll
      for (int kbl = 0; kbl < 8; ++kbl) {
        int kb = kb0 + kbl;
        int maskable = layer ? (kb >= 32) : (kb >= 2);
        short8 v = sv[kbl];
        if (maskable && sdone) v = z8;
        *(short8*)(d + kbl * 2048) = v;   // tile (kbl*4 + wv)
      }
    };
    // issue 16 B loads for half h; tail clamped (L2-hit repeat)
    auto issueB = [&](int h, short8 (&vB)[4][4]) {
      int kk = h * 4;
      #pragma unroll
      for (int kbl = 0; kbl < 4; ++kbl) {
        int kbx = kk + kbl;
        if (kbx > NKB - 1) kbx = NKB - 1;
        #pragma unroll
        for (int ct = 0; ct < 4; ++ct)
          gload(Wf + ((size_t)(cg * NKB + kbx) * 8 + wgc * 4 + ct) * 512 + lane * 8, vB[kbl][ct]);
      }
    };
    auto comp4 = [&](int h, short8 (&vB)[4][4]) {
      int kbc4 = NKB - h * 4; if (kbc4 > 4) kbc4 = 4;
      int bo = ((h >> 1) & 1) << 14;
      int tb = (h & 1) * 4;
      #pragma unroll
      for (int kbl = 0; kbl < 4; ++kbl) if (kbl < kbc4) {
        short8 af0 = *(const short8*)&smem[bo + ((tb + kbl) * 4 + wgr * 2 + 0) * 512 + lane * 8];
        short8 af1 = *(const short8*)&smem[bo + ((tb + kbl) * 4 + wgr * 2 + 1) * 512 + lane * 8];
        #pragma unroll
        for (int ct = 0; ct < 4; ++ct) {
          acc0[ct] = MFMA(af0, vB[kbl][ct], acc0[ct]);
          acc1[ct] = MFMA(af1, vB[kbl][ct], acc1[ct]);
        }
      }
    };

    // ---- prologue: B(0)[16] A(0)[8] B(1)[16] in flight = 40; retire B0+A0, keep B1 ----
    issueB(0, vBa);
    issueA(0);
    issueB(1, vBb);
    asm volatile("s_waitcnt vmcnt(16)" : TIES_SV, TIES_VB(vBa) :: "memory");
    __builtin_amdgcn_sched_barrier(0);
    commitA(0);
    __syncthreads();

    // ---- main loop: invariant at top = B(2c+1) [16] in flight ----
    for (int c = 0; c < NC - 1; ++c) {
      issueA(c + 1);                                   // -> 24
      comp4(2 * c, vBa);
      issueB(2 * c + 2, vBa);                          // -> 40
      asm volatile("s_waitcnt vmcnt(24)" : TIES_VB(vBb) :: "memory");  // B(2c+1) ready
      __builtin_amdgcn_sched_barrier(0);
      comp4(2 * c + 1, vBb);
      issueB(2 * c + 3, vBb);                          // -> 40
      asm volatile("s_waitcnt vmcnt(32)" : TIES_SV :: "memory");       // A(c+1) ready
      __builtin_amdgcn_sched_barrier(0);
      commitA(c + 1);
      asm volatile("s_waitcnt vmcnt(16)" : TIES_VB(vBa) :: "memory");  // B(2c+2) ready
      __builtin_amdgcn_sched_barrier(0);
      __syncthreads();                                 // leaves B(2c+3) [16] in flight
    }
    // ---- tail chunk ----
    {
      int c = NC - 1;
      comp4(2 * c, vBa);
      asm volatile("s_waitcnt vmcnt(0)" : TIES_VB(vBb) :: "memory");
      __builtin_amdgcn_sched_barrier(0);
      if (2 * c + 1 < NH) comp4(2 * c + 1, vBb);
      __syncthreads();   // protect gl alias (buffer 0) from in-flight comp reads
    }

    // epilogue: gates -> LDS gl[row64][col128]
    #pragma unroll
    for (int ct = 0; ct < 4; ++ct)
      #pragma unroll
      for (int rgi = 0; rgi < 4; ++rgi) {
        int row0 = wgr * 32 + quad * 4 + rgi;
        int col = wgc * 64 + ct * 16 + c16;
        gl[row0 * 128 + col] = acc0[ct][rgi];
        gl[(row0 + 16) * 128 + col] = acc1[ct][rgi];
      }
    __syncthreads();

    {
      int row = tid >> 2;           // 0..63
      int q = tid & 3;
      int h8 = q * 8;
      int rowg = rg * 64 + row;
      int H0 = cg * 32 + h8;
      const float* glp = gl + row * 128;
      float m = done[t * BATCH + rowg] ? 0.f : 1.f;
      short8 hv;
      float h2a[8];
      #pragma unroll
      for (int j = 0; j < 8; ++j) {
        float ivv = glp[h8 + j]      + bs[H0 + j];
        float fvv = glp[32 + h8 + j] + bs[HID + H0 + j];
        float gvv = glp[64 + h8 + j] + bs[2*HID + H0 + j];
        float ovv = glp[96 + h8 + j] + bs[3*HID + H0 + j];
        float c2 = sigm(fvv) * (creg[j] * m) + sigm(ivv) * tanh_f(gvv);
        float h2 = sigm(ovv) * tanh_f(c2);
        creg[j] = c2;
        h2a[j] = h2;
        ((u16*)&hv)[j] = f2b(h2);
      }
      size_t off = (size_t)((rg * 4 + (row >> 4)) * 32 + cg) * 512 + (size_t)(q * 16 + (row & 15)) * 8;
      if (layer == 0) store_cg(h0r + (size_t)((t + 1) & (RING-1)) * 262144 + off, hv);
      else            store_cg(h1u + (size_t)(t + 1) * 262144 + off, hv);
      if (t == SEQ - 1) {
        float* dh = dout + 32768 + (size_t)layer * LSZ + (size_t)rowg * HID + H0;
        float* dc = dout + 32768 + 2 * LSZ + (size_t)layer * LSZ + (size_t)rowg * HID + H0;
        #pragma unroll
        for (int j = 0; j < 8; ++j) { dh[j] = h2a[j]; dc[j] = creg[j]; }
      }
    }
    wait_vm0();          // drain h stores (write-through acked)
    __syncthreads();
    if (tid == 0) flag_set(myf, t + 1);
  }
}

// ---------------- LayerNorm row stats (reads h1u frag layout) ----------------
__global__ void ln_stats(const u16* __restrict__ h1u, float* __restrict__ mu, float* __restrict__ rstd) {
  int R = blockIdx.x * 4 + (threadIdx.x >> 6);
  int l = threadIdx.x & 63;
  int t = R >> 8, brow = R & 255, grt = brow >> 4, rl = brow & 15;
  const u16* base = h1u + (size_t)(t + 1) * 262144 + (size_t)(grt * 32 + (l >> 1)) * 512;
  int q2 = (l & 1) * 2;
  short8 v0 = *(const short8*)(base + (q2 * 16 + rl) * 8);
  short8 v1 = *(const short8*)(base + ((q2 + 1) * 16 + rl) * 8);
  float s = 0.f, q = 0.f;
  #pragma unroll
  for (int e = 0; e < 8; ++e) {
    float a = b2f((u16)v0[e]); s += a; q += a*a;
    float b = b2f((u16)v1[e]); s += b; q += b*b;
  }
  for (int o = 32; o > 0; o >>= 1) { s += __shfl_xor(s, o); q += __shfl_xor(q, o); }
  if (l == 0) {
    float mm = s * (1.f/1024.f);
    float var = q * (1.f/1024.f) - mm*mm;
    mu[R] = mm; rstd[R] = rsqrtf(var + 1e-5f);
  }
}

// ---------------- MLP GEMM: 128x128 tile, amode1 = A in h1u frag layout ----------------
__global__ __launch_bounds__(512, 4) void mlp_gemm(
    const u16* __restrict__ A, int lda, int amode,
    const u16* __restrict__ B, int K, int N,
    u16* __restrict__ out, int ldo, int mode, int swiz,
    const float* __restrict__ mu, const float* __restrict__ rstd,
    const float* __restrict__ S1v, const float* __restrict__ bias)
{
  int nt, mtb;
  if (swiz) { int p = blockIdx.x * gridDim.y + blockIdx.y; nt = p & 3; mtb = p >> 2; }
  else { nt = blockIdx.x; mtb = blockIdx.y; }
  const int tid = threadIdx.x, lane = tid & 63, wv = tid >> 6;
  const int quad = lane >> 4, c16 = lane & 15;
  __shared__ __align__(16) u16 Am[16384], Bm[16384];
  f32x4 acc[8];
  #pragma unroll
  for (int i = 0; i < 8; ++i) acc[i] = (f32x4){0.f,0.f,0.f,0.f};

  int arow[4], akl[4], bcol[4];
  #pragma unroll
  for (int i = 0; i < 4; ++i) {
    int s = tid + i * 512, sub = s >> 6, lp = s & 63;
    int ks = sub >> 3, u = sub & 7;
    arow[i] = mtb * 128 + u * 16 + (lp & 15);
    akl[i]  = ks * 32 + (lp >> 4) * 8;
    bcol[i] = nt * 128 + u * 16 + (lp & 15);
  }
  short8 vA[4], vB[4];
  const short8 z8 = {0,0,0,0,0,0,0,0};
  const int NCH = K >> 7;
  auto load_stage = [&](int ci) {
    int kc = ci << 7;
    #pragma unroll
    for (int i = 0; i < 4; ++i) {
      if (amode) {
        int R = arow[i], k = kc + akl[i];
        const u16* p = A + (size_t)((R >> 8) + 1) * 262144
                         + (size_t)(((R >> 4) & 15) * 32 + (k >> 5)) * 512
                         + (size_t)((((k >> 3) & 3) * 16 + (R & 15)) * 8);
        vA[i] = *(const short8*)p;
      } else {
        vA[i] = *(const short8*)(A + (size_t)arow[i] * lda + kc + akl[i]);
      }
      vB[i] = (bcol[i] < N) ? *(const short8*)(B + (size_t)bcol[i] * K + kc + akl[i]) : z8;
    }
  };
  load_stage(0);
  for (int ci = 0; ci < NCH; ++ci) {
    #pragma unroll
    for (int i = 0; i < 4; ++i) {
      *(short8*)&Am[(size_t)(tid + i*512) * 8] = vA[i];
      *(short8*)&Bm[(size_t)(tid + i*512) * 8] = vB[i];
    }
    __syncthreads();
    if (ci + 1 < NCH) load_stage(ci + 1);
    #pragma unroll
    for (int ks = 0; ks < 4; ++ks) {
      short8 bf = *(const short8*)&Bm[((ks*8 + wv)*64 + lane) * 8];
      #pragma unroll
      for (int rt = 0; rt < 8; ++rt) {
        short8 af = *(const short8*)&Am[((ks*8 + rt)*64 + lane) * 8];
        acc[rt] = MFMA(af, bf, acc[rt]);
      }
    }
    __syncthreads();
  }
  int col = nt * 128 + wv * 16 + c16;
  if (col < N) {
    #pragma unroll
    for (int rt = 0; rt < 8; ++rt) {
      #pragma unroll
      for (int rgi = 0; rgi < 4; ++rgi) {
        int row = mtb * 128 + rt * 16 + quad * 4 + rgi;
        float v = acc[rt][rgi];
        if (mode == 0) v = v * rstd[row] - mu[row] * rstd[row] * S1v[col] + bias[col];
        else           v = v + bias[col];
        v = eluf(v);
        out[(size_t)row * ldo + col] = f2b(v);
      }
    }
  }
}

__global__ void value_head(const u16* __restrict__ a3, const float* __restrict__ wv,
                           const float* __restrict__ bv, float* __restrict__ dout) {
  int row = blockIdx.x * 256 + threadIdx.x;
  const short8* p = (const short8*)(a3 + (size_t)row * 64);
  float s = bv[0];
  #pragma unroll
  for (int j = 0; j < 8; ++j) {
    short8 v = p[j];
    #pragma unroll
    for (int e = 0; e < 8; ++e) s += b2f((u16)v[e]) * wv[j*8+e];
  }
  dout[row] = s;
}

extern "C" void kernel_launch(void* const* d_in, const int* in_sizes, int n_in,
                              void* d_out, int out_size, void* d_ws, size_t ws_size,
                              hipStream_t stream) {
  (void)in_sizes; (void)n_in; (void)out_size; (void)ws_size;
  const float* x    = (const float*)d_in[0];
  const int*   done = (const int*)d_in[1];
  const float* h0in = (const float*)d_in[2];
  const float* c0in = (const float*)d_in[3];
  const float* wih0 = (const float*)d_in[4];
  const float* whh0 = (const float*)d_in[5];
  const float* bih0 = (const float*)d_in[6];
  const float* bhh0 = (const float*)d_in[7];
  const float* wih1 = (const float*)d_in[8];
  const float* whh1 = (const float*)d_in[9];
  const float* bih1 = (const float*)d_in[10];
  const float* bhh1 = (const float*)d_in[11];
  const float* lng  = (const float*)d_in[12];
  const float* lnb  = (const float*)d_in[13];
  const float* w1   = (const float*)d_in[14];
  const float* b1   = (const float*)d_in[15];
  const float* w2   = (const float*)d_in[16];
  const float* b2   = (const float*)d_in[17];
  const float* w3   = (const float*)d_in[18];
  const float* b3   = (const float*)d_in[19];
  const float* wvp  = (const float*)d_in[20];
  const float* bvp  = (const float*)d_in[21];
  float* dout = (float*)d_out;
  char* ws = (char*)d_ws;

  u16*   w0f  = (u16*)(ws + OFF_W0F);
  u16*   w1f  = (u16*)(ws + OFF_W1F);
  u16*   xf   = (u16*)(ws + OFF_XF);
  u16*   h0r  = (u16*)(ws + OFF_H0R);
  u16*   h1u  = (u16*)(ws + OFF_H1U);
  float* bs0  = (float*)(ws + OFF_BS0);
  float* bs1  = (float*)(ws + OFF_BS1);
  int*   flg  = (int*)(ws + OFF_FLG);
  float* mu   = (float*)(ws + OFF_MU);
  float* rstd = (float*)(ws + OFF_RSTD);
  u16*   w1ln = (u16*)(ws + OFF_W1LN);
  float* s1   = (float*)(ws + OFF_S1);
  float* b1p  = (float*)(ws + OFF_B1P);
  u16*   w2b  = (u16*)(ws + OFF_W2B);
  u16*   w3b  = (u16*)(ws + OFF_W3B);
  u16*   a1   = (u16*)(ws + OFF_A1);
  u16*   a2   = (u16*)(ws + OFF_A2);
  u16*   a3   = (u16*)(ws + OFF_A3);

  prep_wf<<<256, 256, 0, stream>>>(wih0, whh0, w0f, 34, 64);
  prep_wf<<<256, 256, 0, stream>>>(wih1, whh1, w1f, 64, 1024);
  prep_w1ln<<<512, 256, 0, stream>>>(w1, lng, lnb, b1, w1ln, s1, b1p);
  prep_misc<<<12609, 256, 0, stream>>>(bih0, bhh0, bih1, bhh1, x, h0in, w2, w3,
                                       bs0, bs1, xf, h0r, h1u, w2b, w3b, flg);

  lstm_persist<<<256, 256, 0, stream>>>(w0f, w1f, xf, h0r, h1u, c0in,
                                        bs0, bs1, done, flg, dout);

  ln_stats<<<8192, 256, 0, stream>>>(h1u, mu, rstd);
  mlp_gemm<<<dim3(8, 128), 512, 0, stream>>>(h1u, 0, 1, w1ln, 1024, 512, a1, 512, 0, 1, mu, rstd, s1, b1p);
  mlp_gemm<<<dim3(1, 256), 512, 0, stream>>>(a1, 512, 0, w2b, 512, 128, a2, 128, 1, 0, mu, rstd, s1, b2);
  mlp_gemm<<<dim3(1, 256), 512, 0, stream>>>(a2, 128, 0, w3b, 128, 64, a3, 64, 1, 0, mu, rstd, s1, b3);
  value_head<<<128, 256, 0, stream>>>(a3, wvp, bvp, dout);
}